// Round 1
// baseline (92.965 us; speedup 1.0000x reference)
//
#include <hip/hip_runtime.h>

#define MARGIN 0.2f
#define BLOCKS 2048
#define THREADS 256

// ---------------------------------------------------------------------------
// Workspace layout (doubles): ws[0] = sum(similarities), ws[1] = sum(loss)
// ---------------------------------------------------------------------------

__global__ void init_ws_kernel(double* __restrict__ ws) {
    if (threadIdx.x == 0) {
        ws[0] = 0.0;
        ws[1] = 0.0;
    }
}

__device__ __forceinline__ void block_reduce_atomic(double v, double* dst) {
    // wave(64)-level butterfly-free down-reduce
    for (int off = 32; off > 0; off >>= 1)
        v += __shfl_down(v, off);
    __shared__ double lds[THREADS / 64];
    const int wave = threadIdx.x >> 6;
    if ((threadIdx.x & 63) == 0) lds[wave] = v;
    __syncthreads();
    if (threadIdx.x == 0) {
        double t = 0.0;
        #pragma unroll
        for (int w = 0; w < THREADS / 64; ++w) t += lds[w];
        atomicAdd(dst, t);  // device-scope f64 atomic on gfx950
    }
}

// ---------------------------------------------------------------------------
// Pass 1: sum of all elements
// ---------------------------------------------------------------------------
__global__ __launch_bounds__(THREADS) void sum_kernel(
    const float* __restrict__ in, long n, double* __restrict__ ws) {
    const long n4 = n >> 2;
    const float4* __restrict__ in4 = reinterpret_cast<const float4*>(in);
    const long idx = (long)blockIdx.x * blockDim.x + threadIdx.x;
    const long stride = (long)gridDim.x * blockDim.x;

    float s = 0.0f;
    for (long i = idx; i < n4; i += stride) {
        float4 v = in4[i];
        s += (v.x + v.y) + (v.z + v.w);
    }
    // scalar tail (n not multiple of 4) — only block 0
    if (blockIdx.x == 0) {
        long tail_start = n4 << 2;
        for (long i = tail_start + threadIdx.x; i < n; i += blockDim.x)
            s += in[i];
    }
    block_reduce_atomic((double)s, &ws[0]);
}

// ---------------------------------------------------------------------------
// Pass 2: sum of relu(margin - |x - mean|)
// ---------------------------------------------------------------------------
__global__ __launch_bounds__(THREADS) void loss_kernel(
    const float* __restrict__ in, long n, double* __restrict__ ws) {
    const float mean = (float)(ws[0] / (double)n);

    const long n4 = n >> 2;
    const float4* __restrict__ in4 = reinterpret_cast<const float4*>(in);
    const long idx = (long)blockIdx.x * blockDim.x + threadIdx.x;
    const long stride = (long)gridDim.x * blockDim.x;

    float s = 0.0f;
    for (long i = idx; i < n4; i += stride) {
        float4 v = in4[i];
        s += fmaxf(MARGIN - fabsf(v.x - mean), 0.0f);
        s += fmaxf(MARGIN - fabsf(v.y - mean), 0.0f);
        s += fmaxf(MARGIN - fabsf(v.z - mean), 0.0f);
        s += fmaxf(MARGIN - fabsf(v.w - mean), 0.0f);
    }
    if (blockIdx.x == 0) {
        long tail_start = n4 << 2;
        for (long i = tail_start + threadIdx.x; i < n; i += blockDim.x)
            s += fmaxf(MARGIN - fabsf(in[i] - mean), 0.0f);
    }
    block_reduce_atomic((double)s, &ws[1]);
}

// ---------------------------------------------------------------------------
// Finalize: out = loss_sum / n
// ---------------------------------------------------------------------------
__global__ void finalize_kernel(const double* __restrict__ ws,
                                float* __restrict__ out, long n) {
    if (threadIdx.x == 0)
        out[0] = (float)(ws[1] / (double)n);
}

extern "C" void kernel_launch(void* const* d_in, const int* in_sizes, int n_in,
                              void* d_out, int out_size, void* d_ws, size_t ws_size,
                              hipStream_t stream) {
    const float* sims = (const float*)d_in[0];
    const long n = (long)in_sizes[0];
    double* ws = (double*)d_ws;
    float* out = (float*)d_out;

    init_ws_kernel<<<1, 64, 0, stream>>>(ws);
    sum_kernel<<<BLOCKS, THREADS, 0, stream>>>(sims, n, ws);
    loss_kernel<<<BLOCKS, THREADS, 0, stream>>>(sims, n, ws);
    finalize_kernel<<<1, 64, 0, stream>>>(ws, out, n);
}

// Round 2
// 53.542 us; speedup vs baseline: 1.7363x; 1.7363x over previous
//
#include <hip/hip_runtime.h>

#define MARGIN 0.2f
#define NBLK 2048
#define NTHR 256

// Workspace: per-block f64 partials (every slot written each call -> no init
// kernel, no atomics, deterministic summation order).
struct Ws {
    double p1[NBLK];   // per-block partial sums of similarities
    double p2[NBLK];   // per-block partial sums of loss
};

// Reduce v across the block; result valid in thread 0 only.
// Safe to call twice per kernel IF a __syncthreads() separates the calls
// after thread 0 has consumed the result (we do that below).
__device__ __forceinline__ double block_reduce(double v) {
    #pragma unroll
    for (int off = 32; off > 0; off >>= 1)
        v += __shfl_down(v, off);
    __shared__ double lds[NTHR / 64];
    const int w = threadIdx.x >> 6;
    if ((threadIdx.x & 63) == 0) lds[w] = v;
    __syncthreads();
    double t = 0.0;
    if (threadIdx.x == 0) {
        #pragma unroll
        for (int i = 0; i < NTHR / 64; ++i) t += lds[i];
    }
    return t;
}

// ---------------------------------------------------------------------------
// Kernel A: per-block partial sums of the input
// ---------------------------------------------------------------------------
__global__ __launch_bounds__(NTHR) void sum_kernel(
    const float* __restrict__ in, long n, Ws* __restrict__ ws) {
    const long n4 = n >> 2;
    const float4* __restrict__ in4 = reinterpret_cast<const float4*>(in);
    const long idx = (long)blockIdx.x * NTHR + threadIdx.x;
    const long stride = (long)gridDim.x * NTHR;

    float s = 0.0f;
    long i = idx;
    // 4 independent loads in flight per wave
    for (; i + 3 * stride < n4; i += 4 * stride) {
        float4 a = in4[i];
        float4 b = in4[i + stride];
        float4 c = in4[i + 2 * stride];
        float4 d = in4[i + 3 * stride];
        s += ((a.x + a.y) + (a.z + a.w)) + ((b.x + b.y) + (b.z + b.w));
        s += ((c.x + c.y) + (c.z + c.w)) + ((d.x + d.y) + (d.z + d.w));
    }
    for (; i < n4; i += stride) {
        float4 v = in4[i];
        s += (v.x + v.y) + (v.z + v.w);
    }
    // scalar tail (n % 4) — block 0 only
    if (blockIdx.x == 0) {
        for (long j = (n4 << 2) + threadIdx.x; j < n; j += NTHR)
            s += in[j];
    }
    double t = block_reduce((double)s);
    if (threadIdx.x == 0) ws->p1[blockIdx.x] = t;
}

// ---------------------------------------------------------------------------
// Kernel B: each block reduces p1 -> mean (16 KB L2-resident read), then
// computes per-block partial loss sums
// ---------------------------------------------------------------------------
__global__ __launch_bounds__(NTHR) void loss_kernel(
    const float* __restrict__ in, long n, Ws* __restrict__ ws) {
    // mean from partials (deterministic order)
    double m = 0.0;
    #pragma unroll
    for (int i = threadIdx.x; i < NBLK; i += NTHR) m += ws->p1[i];
    m = block_reduce(m);
    __shared__ double s_mean;
    if (threadIdx.x == 0) s_mean = m / (double)n;
    __syncthreads();               // also protects block_reduce's LDS reuse
    const float mean = (float)s_mean;

    const long n4 = n >> 2;
    const float4* __restrict__ in4 = reinterpret_cast<const float4*>(in);
    const long idx = (long)blockIdx.x * NTHR + threadIdx.x;
    const long stride = (long)gridDim.x * NTHR;

    float s = 0.0f;
    long i = idx;
    for (; i + 3 * stride < n4; i += 4 * stride) {
        float4 a = in4[i];
        float4 b = in4[i + stride];
        float4 c = in4[i + 2 * stride];
        float4 d = in4[i + 3 * stride];
        s += fmaxf(MARGIN - fabsf(a.x - mean), 0.0f) + fmaxf(MARGIN - fabsf(a.y - mean), 0.0f);
        s += fmaxf(MARGIN - fabsf(a.z - mean), 0.0f) + fmaxf(MARGIN - fabsf(a.w - mean), 0.0f);
        s += fmaxf(MARGIN - fabsf(b.x - mean), 0.0f) + fmaxf(MARGIN - fabsf(b.y - mean), 0.0f);
        s += fmaxf(MARGIN - fabsf(b.z - mean), 0.0f) + fmaxf(MARGIN - fabsf(b.w - mean), 0.0f);
        s += fmaxf(MARGIN - fabsf(c.x - mean), 0.0f) + fmaxf(MARGIN - fabsf(c.y - mean), 0.0f);
        s += fmaxf(MARGIN - fabsf(c.z - mean), 0.0f) + fmaxf(MARGIN - fabsf(c.w - mean), 0.0f);
        s += fmaxf(MARGIN - fabsf(d.x - mean), 0.0f) + fmaxf(MARGIN - fabsf(d.y - mean), 0.0f);
        s += fmaxf(MARGIN - fabsf(d.z - mean), 0.0f) + fmaxf(MARGIN - fabsf(d.w - mean), 0.0f);
    }
    for (; i < n4; i += stride) {
        float4 v = in4[i];
        s += fmaxf(MARGIN - fabsf(v.x - mean), 0.0f) + fmaxf(MARGIN - fabsf(v.y - mean), 0.0f);
        s += fmaxf(MARGIN - fabsf(v.z - mean), 0.0f) + fmaxf(MARGIN - fabsf(v.w - mean), 0.0f);
    }
    if (blockIdx.x == 0) {
        for (long j = (n4 << 2) + threadIdx.x; j < n; j += NTHR)
            s += fmaxf(MARGIN - fabsf(in[j] - mean), 0.0f);
    }
    double t = block_reduce((double)s);
    if (threadIdx.x == 0) ws->p2[blockIdx.x] = t;
}

// ---------------------------------------------------------------------------
// Kernel C: reduce p2 -> out (single block)
// ---------------------------------------------------------------------------
__global__ __launch_bounds__(NTHR) void finalize_kernel(
    const Ws* __restrict__ ws, float* __restrict__ out, long n) {
    double m = 0.0;
    #pragma unroll
    for (int i = threadIdx.x; i < NBLK; i += NTHR) m += ws->p2[i];
    m = block_reduce(m);
    if (threadIdx.x == 0) out[0] = (float)(m / (double)n);
}

extern "C" void kernel_launch(void* const* d_in, const int* in_sizes, int n_in,
                              void* d_out, int out_size, void* d_ws, size_t ws_size,
                              hipStream_t stream) {
    const float* sims = (const float*)d_in[0];
    const long n = (long)in_sizes[0];
    Ws* ws = (Ws*)d_ws;
    float* out = (float*)d_out;

    sum_kernel<<<NBLK, NTHR, 0, stream>>>(sims, n, ws);
    loss_kernel<<<NBLK, NTHR, 0, stream>>>(sims, n, ws);
    finalize_kernel<<<1, NTHR, 0, stream>>>(ws, out, n);
}